// Round 15
// baseline (84585.114 us; speedup 1.0000x reference)
//
#include <hip/hip_runtime.h>
#include <cmath>

#define NBLK 256
#define NTHR 1024
#define Bv 64
#define Lv 4
#define Hv 512
#define Tv 256
#define G4 2048

// ws layout (bytes)
#define WT_OFF   0u                       // [256 blk][4 l][8 col][1024 k] f32 = 32 MB
#define HT_OFF   (33554432u)              // hT [2 par][4 l][128 k4][64 b][4] f32 = 1 MB
#define YT_OFF   (HT_OFF + 1048576u)      // yT [128][64][4] f32 = 128 KB
#define BIAS_OFF (YT_OFF + 131072u)       // biasC [4][2048] f32 = 32 KB
#define BAR_OFF  (BIAS_OFF + 32768u)      // bar8: 8 counters @ 64B stride

__device__ __forceinline__ float sigmoidf_(float x) {
    return 1.0f / (1.0f + __expf(-x));
}
__device__ __forceinline__ float lo32f(unsigned long long v) {
    return __uint_as_float((unsigned)(v & 0xffffffffu));
}
__device__ __forceinline__ float hi32f(unsigned long long v) {
    return __uint_as_float((unsigned)(v >> 32));
}
// async 16B global -> LDS (dest = wave-uniform base + lane*16)
__device__ __forceinline__ void gload_lds16(const float* g, float* l) {
    __builtin_amdgcn_global_load_lds(
        (const __attribute__((address_space(1))) void*)g,
        (__attribute__((address_space(3))) void*)l, 16, 0, 0);
}

// wt[bid][l][col][k]: col = 4*(hn&1)+g for hn = bid*2 + (col>>2);
// k<512 from Wih[l][g*512+hn][k] (x part), k>=512 from Whh (h part)
__global__ __launch_bounds__(256) void prep_wt(const float* __restrict__ Wih,
                                               const float* __restrict__ Whh,
                                               float* __restrict__ wt) {
    int bid = blockIdx.x, tid = threadIdx.x;
    float* dst = wt + (size_t)bid * (4 * 8 * 1024);
    int k = tid * 4;
#pragma unroll
    for (int l = 0; l < 4; ++l)
#pragma unroll
        for (int col = 0; col < 8; ++col) {
            int hn = bid * 2 + (col >> 2);
            int g  = col & 3;
            const float* src = (k < 512)
                ? (Wih + ((size_t)l * G4 + g * Hv + hn) * Hv + k)
                : (Whh + ((size_t)l * G4 + g * Hv + hn) * Hv + (k - 512));
            *(float4*)(dst + (size_t)(l * 8 + col) * 1024 + k) = *(const float4*)src;
        }
}

// biasC[l][4*hn+g] = bih[l][g*512+hn] + bhh[l][g*512+hn]
__global__ void prep_bias(const float* __restrict__ bih, const float* __restrict__ bhh,
                          float* __restrict__ biasC) {
    int idx = blockIdx.x * 256 + threadIdx.x;       // 8192
    int l = idx >> 11, gi = idx & 2047;
    int hn = gi >> 2, g = gi & 3;
    biasC[idx] = bih[l * G4 + g * Hv + hn] + bhh[l * G4 + g * Hv + hn];
}

// yT[k4][b][sub] = y[b][4*k4+sub]; hT[1][l][k4][b][sub] = h0[l][b][4*k4+sub]
__global__ void prep_act(const float* __restrict__ y, const float* __restrict__ h0,
                         float* __restrict__ yT, float* __restrict__ hT) {
    int idx = blockIdx.x * 256 + threadIdx.x;
    if (idx < 32768) {
        int k4 = idx >> 8, b = (idx >> 2) & 63, sub = idx & 3;
        yT[idx] = y[b * Hv + k4 * 4 + sub];
    } else if (idx < 32768 + 131072) {
        int r2 = idx - 32768;
        int l = r2 >> 15, r = r2 & 32767;
        int k4 = r >> 8, b = (r >> 2) & 63, sub = r & 3;
        hT[(size_t)(4 + l) * 32768 + r] = h0[((size_t)l * Bv + b) * Hv + k4 * 4 + sub];
    }
}

// Persistent kernel, 1024 phases. vs R13 (all f32, proven act/W paths):
//  - thread k-mapping = 32 h-k + 32 x-k: the h-half dot (data from phase p-4)
//    runs BEFORE the inter-block wait; barrier latency hides under it
//  - inter-block wait (tid<8 spin, R13-proven) moved mid-phase
//  - 64-thread epilogue computes both h-units; packed u64 hT store
__global__ __launch_bounds__(NTHR) void lstm_persist(
    const float* __restrict__ wt, const float* __restrict__ biasC,
    const float* __restrict__ yT, const float* __restrict__ c0,
    float* __restrict__ hT, float* __restrict__ out,
    int* __restrict__ bar8)
{
    const int bid  = blockIdx.x;
    const int tid  = threadIdx.x;
    const int b    = tid & 63;
    const int lane = tid & 63;
    const int wv   = tid >> 6;
    const int s    = __builtin_amdgcn_readfirstlane(wv);   // 0..15 wave-uniform

    __shared__ float  wstg[2][8192];   // 64 KB double-buffered W slice [col][k]
    __shared__ float4 redA[16][64];    // cols 0..3 (hn=0)
    __shared__ float4 redB[16][64];    // cols 4..7 (hn=1)
    __shared__ float  cst[4][2][64];   // c state [l][hn][b]

    const float* wtB = wt + (size_t)bid * 32768;
    #define STAGE(ls, bn) {                                              \
        const float* g_ = wtB + (ls) * 8192 + wv * 512 + lane * 4;       \
        gload_lds16(g_,       &wstg[bn][wv * 512]);                      \
        gload_lds16(g_ + 256, &wstg[bn][wv * 512 + 256]);                \
    }

    if (tid < 512) {
        int l = tid >> 7, hn = (tid >> 6) & 1, bb = tid & 63;
        cst[l][hn][bb] = c0[((size_t)l * Bv + bb) * Hv + bid * 2 + hn];
    }
    STAGE(0, 0);
    __syncthreads();        // drains STAGE (vmcnt) + cst writes

    for (int p = 0; p < Tv * Lv; ++p) {
        const int t = p >> 2, l = p & 3;
        const int par = t & 1, ppar = par ^ 1;
        const int cur = p & 1;

        // issue next phase's W staging into the other buffer (fully async)
        if (p + 1 < Tv * Lv) STAGE((p + 1) & 3, cur ^ 1);

        const float* wl = wstg[cur] + s * 32;
        float acc[8];
#pragma unroll
        for (int c = 0; c < 8; ++c) acc[c] = 0.f;

        // ---- h-half: plane written at phase p-4 (or prep) — no wait needed
        {
            const float* hpl = hT + (size_t)(ppar * 4 + l) * 32768;
            const unsigned long long* aq =
                (const unsigned long long*)hpl + (size_t)s * 1024 + b * 2;
            float av[32];
#pragma unroll
            for (int jj = 0; jj < 8; ++jj) {
                unsigned long long lo = __hip_atomic_load(aq + (size_t)jj * 128,
                                          __ATOMIC_RELAXED, __HIP_MEMORY_SCOPE_AGENT);
                unsigned long long hi = __hip_atomic_load(aq + (size_t)jj * 128 + 1,
                                          __ATOMIC_RELAXED, __HIP_MEMORY_SCOPE_AGENT);
                av[jj * 4 + 0] = lo32f(lo);
                av[jj * 4 + 1] = hi32f(lo);
                av[jj * 4 + 2] = lo32f(hi);
                av[jj * 4 + 3] = hi32f(hi);
            }
#pragma unroll
            for (int c = 0; c < 8; ++c) {
                const float* wp = wl + c * 1024 + 512;   // h part of W
                float sum = acc[c];
#pragma unroll
                for (int k = 0; k < 32; ++k)
                    sum = fmaf(wp[k], av[k], sum);
                acc[c] = sum;
            }
        }

        // ---- inter-block wait for phase p-1 (latency hidden by h-half) ----
        if (p > 0) {
            if (tid < 8) {
                const int target = 32 * p;
                while (__hip_atomic_load(&bar8[tid * 16], __ATOMIC_RELAXED,
                                         __HIP_MEMORY_SCOPE_AGENT) < target) {}
            }
            __syncthreads();
        }

        // ---- x-half: plane written at phase p-1 ----
        {
            const float* xpl = (l == 0)
                ? (t == 0 ? yT : hT + (size_t)(ppar * 4 + 3) * 32768)
                : hT + (size_t)(par * 4 + (l - 1)) * 32768;
            const unsigned long long* aq =
                (const unsigned long long*)xpl + (size_t)s * 1024 + b * 2;
            float av[32];
#pragma unroll
            for (int jj = 0; jj < 8; ++jj) {
                unsigned long long lo = __hip_atomic_load(aq + (size_t)jj * 128,
                                          __ATOMIC_RELAXED, __HIP_MEMORY_SCOPE_AGENT);
                unsigned long long hi = __hip_atomic_load(aq + (size_t)jj * 128 + 1,
                                          __ATOMIC_RELAXED, __HIP_MEMORY_SCOPE_AGENT);
                av[jj * 4 + 0] = lo32f(lo);
                av[jj * 4 + 1] = hi32f(lo);
                av[jj * 4 + 2] = lo32f(hi);
                av[jj * 4 + 3] = hi32f(hi);
            }
#pragma unroll
            for (int c = 0; c < 8; ++c) {
                const float* wp = wl + c * 1024;         // x part of W
                float sum = acc[c];
#pragma unroll
                for (int k = 0; k < 32; ++k)
                    sum = fmaf(wp[k], av[k], sum);
                acc[c] = sum;
            }
        }

        redA[s][b] = make_float4(acc[0], acc[1], acc[2], acc[3]);
        redB[s][b] = make_float4(acc[4], acc[5], acc[6], acc[7]);
        __syncthreads();   // red ready; also drains STAGE(p+1) (vmcnt)

        // ---- epilogue: 64 threads, both h-units, packed u64 store ----
        if (tid < 64) {
            const int b2 = tid;
            float g0 = 0.f, g1 = 0.f, g2 = 0.f, g3 = 0.f;
            float g4 = 0.f, g5 = 0.f, g6 = 0.f, g7 = 0.f;
#pragma unroll
            for (int ss = 0; ss < 16; ++ss) {
                float4 ra = redA[ss][b2];
                g0 += ra.x; g1 += ra.y; g2 += ra.z; g3 += ra.w;
                float4 rb = redB[ss][b2];
                g4 += rb.x; g5 += rb.y; g6 += rb.z; g7 += rb.w;
            }
            float4 bb0 = *(const float4*)(biasC + l * G4 + bid * 8);
            float4 bb1 = *(const float4*)(biasC + l * G4 + bid * 8 + 4);

            float i0 = sigmoidf_(g0 + bb0.x), f0 = sigmoidf_(g1 + bb0.y);
            float q0 = tanhf(g2 + bb0.z),     o0 = sigmoidf_(g3 + bb0.w);
            float cn0 = f0 * cst[l][0][b2] + i0 * q0;
            cst[l][0][b2] = cn0;
            float h0v = o0 * tanhf(cn0);

            float i1 = sigmoidf_(g4 + bb1.x), f1 = sigmoidf_(g5 + bb1.y);
            float q1 = tanhf(g6 + bb1.z),     o1 = sigmoidf_(g7 + bb1.w);
            float cn1 = f1 * cst[l][1][b2] + i1 * q1;
            cst[l][1][b2] = cn1;
            float h1v = o1 * tanhf(cn1);

            // n0 = 2*bid, n1 = 2*bid+1 are adjacent f32s in the same k4 group
            union { float f[2]; unsigned long long u; } pk;
            pk.f[0] = h0v; pk.f[1] = h1v;
            unsigned long long* dst = (unsigned long long*)hT +
                (size_t)(par * 4 + l) * 16384 +
                (size_t)(bid >> 1) * 128 + b2 * 2 + (bid & 1);
            __hip_atomic_store(dst, pk.u, __ATOMIC_RELAXED,
                               __HIP_MEMORY_SCOPE_AGENT);
            if (l == Lv - 1)
                *(float2*)(out + ((size_t)b2 * Tv + t) * Hv + bid * 2) =
                    make_float2(h0v, h1v);
        }
        __syncthreads();   // epilogue stores drained (vmcnt) before arrival

        if (tid == 0)
            __hip_atomic_fetch_add(&bar8[(bid & 7) * 16], 1,
                                   __ATOMIC_RELEASE, __HIP_MEMORY_SCOPE_AGENT);
    }
    #undef STAGE
}

extern "C" void kernel_launch(void* const* d_in, const int* in_sizes, int n_in,
                              void* d_out, int out_size, void* d_ws, size_t ws_size,
                              hipStream_t stream)
{
    const float* y   = (const float*)d_in[0];
    const float* h0  = (const float*)d_in[1];
    const float* c0  = (const float*)d_in[2];
    const float* Wih = (const float*)d_in[3];
    const float* Whh = (const float*)d_in[4];
    const float* bih = (const float*)d_in[5];
    const float* bhh = (const float*)d_in[6];
    float* out = (float*)d_out;

    char* ws = (char*)d_ws;
    float* wt    = (float*)(ws + WT_OFF);
    float* hT    = (float*)(ws + HT_OFF);
    float* yT    = (float*)(ws + YT_OFF);
    float* biasC = (float*)(ws + BIAS_OFF);
    int*   bar8  = (int*)(ws + BAR_OFF);

    hipMemsetAsync(ws + BAR_OFF, 0, 1024, stream);

    prep_wt<<<NBLK, 256, 0, stream>>>(Wih, Whh, wt);
    prep_bias<<<32, 256, 0, stream>>>(bih, bhh, biasC);
    prep_act<<<(32768 + 131072) / 256, 256, 0, stream>>>(y, h0, yT, hT);

    lstm_persist<<<NBLK, NTHR, 0, stream>>>(wt, biasC, yT, c0, hT, out, bar8);
}

// Round 16
// 49276.019 us; speedup vs baseline: 1.7166x; 1.7166x over previous
//
#include <hip/hip_runtime.h>
#include <cmath>

#define NBLK 256
#define NTHR 1024
#define Bv 64
#define Lv 4
#define Hv 512
#define Tv 256
#define G4 2048

// ws layout (bytes)
#define WT_OFF   0u                       // [256 blk][4 l][8 col][1024 k] f32 = 32 MB
#define HT_OFF   (33554432u)              // hT [2 par][4 l][128 k4][64 b][4] f32 = 1 MB
#define YT_OFF   (HT_OFF + 1048576u)      // yT [128][64][4] f32 = 128 KB
#define BIAS_OFF (YT_OFF + 131072u)       // biasC [4][2048] f32 = 32 KB
#define BAR_OFF  (BIAS_OFF + 32768u)      // bar8: 8 counters @ 64B stride

__device__ __forceinline__ float sigmoidf_(float x) {
    return 1.0f / (1.0f + __expf(-x));
}
// async 16B global -> LDS (dest = wave-uniform base + lane*16)
__device__ __forceinline__ void gload_lds16(const float* g, float* l) {
    __builtin_amdgcn_global_load_lds(
        (const __attribute__((address_space(1))) void*)g,
        (__attribute__((address_space(3))) void*)l, 16, 0, 0);
}

// wt[bid][l][col][k]: col = 4*(hn&1)+g for hn = bid*2 + (col>>2);
// k<512 from Wih[l][g*512+hn][k] (x part), k>=512 from Whh (h part)
__global__ __launch_bounds__(256) void prep_wt(const float* __restrict__ Wih,
                                               const float* __restrict__ Whh,
                                               float* __restrict__ wt) {
    int bid = blockIdx.x, tid = threadIdx.x;
    float* dst = wt + (size_t)bid * (4 * 8 * 1024);
    int k = tid * 4;
#pragma unroll
    for (int l = 0; l < 4; ++l)
#pragma unroll
        for (int col = 0; col < 8; ++col) {
            int hn = bid * 2 + (col >> 2);
            int g  = col & 3;
            const float* src = (k < 512)
                ? (Wih + ((size_t)l * G4 + g * Hv + hn) * Hv + k)
                : (Whh + ((size_t)l * G4 + g * Hv + hn) * Hv + (k - 512));
            *(float4*)(dst + (size_t)(l * 8 + col) * 1024 + k) = *(const float4*)src;
        }
}

// biasC[l][4*hn+g] = bih[l][g*512+hn] + bhh[l][g*512+hn]
__global__ void prep_bias(const float* __restrict__ bih, const float* __restrict__ bhh,
                          float* __restrict__ biasC) {
    int idx = blockIdx.x * 256 + threadIdx.x;       // 8192
    int l = idx >> 11, gi = idx & 2047;
    int hn = gi >> 2, g = gi & 3;
    biasC[idx] = bih[l * G4 + g * Hv + hn] + bhh[l * G4 + g * Hv + hn];
}

// yT[k4][b][sub] = y[b][4*k4+sub]; hT[1][l][k4][b][sub] = h0[l][b][4*k4+sub]
__global__ void prep_act(const float* __restrict__ y, const float* __restrict__ h0,
                         float* __restrict__ yT, float* __restrict__ hT) {
    int idx = blockIdx.x * 256 + threadIdx.x;
    if (idx < 32768) {
        int k4 = idx >> 8, b = (idx >> 2) & 63, sub = idx & 3;
        yT[idx] = y[b * Hv + k4 * 4 + sub];
    } else if (idx < 32768 + 131072) {
        int r2 = idx - 32768;
        int l = r2 >> 15, r = r2 & 32767;
        int k4 = r >> 8, b = (r >> 2) & 63, sub = r & 3;
        hT[(size_t)(4 + l) * 32768 + r] = h0[((size_t)l * Bv + b) * Hv + k4 * 4 + sub];
    }
}

// Persistent kernel — R13 (proven 20.6 ms) with ONE experiment:
// act reads are plain cached float4 loads (L2-amortized per XCD) with a
// single agent-acquire fence (buffer_inv) per phase for coherence; h writes
// stay agent-scope atomic write-through (release-add ordering unchanged).
// W-in-LDS staging makes the per-phase L2 invalidate harmless (R4's failure
// mode — invalidating L2-resident W — is structurally gone).
__global__ __launch_bounds__(NTHR) void lstm_persist(
    const float* __restrict__ wt, const float* __restrict__ biasC,
    const float* __restrict__ yT, const float* __restrict__ c0,
    float* __restrict__ hT, float* __restrict__ out,
    int* __restrict__ bar8)
{
    const int bid  = blockIdx.x;
    const int tid  = threadIdx.x;
    const int b    = tid & 63;
    const int lane = tid & 63;
    const int wv   = tid >> 6;
    const int s    = __builtin_amdgcn_readfirstlane(wv);   // 0..15 wave-uniform

    __shared__ float  wstg[2][8192];   // 64 KB double-buffered W slice [col][k]
    __shared__ float4 redA[16][64];    // cols 0..3 (hn=0)
    __shared__ float4 redB[16][64];    // cols 4..7 (hn=1)
    __shared__ float  cst[4][2][64];   // c state [l][hn][b]

    const float* wtB = wt + (size_t)bid * 32768;
    #define STAGE(ls, bn) {                                              \
        const float* g_ = wtB + (ls) * 8192 + wv * 512 + lane * 4;       \
        gload_lds16(g_,       &wstg[bn][wv * 512]);                      \
        gload_lds16(g_ + 256, &wstg[bn][wv * 512 + 256]);                \
    }

    if (tid < 512) {
        int l = tid >> 7, hn = (tid >> 6) & 1, bb = tid & 63;
        cst[l][hn][bb] = c0[((size_t)l * Bv + bb) * Hv + bid * 2 + hn];
    }
    STAGE(0, 0);
    __syncthreads();        // drains STAGE (vmcnt) + cst writes

    for (int p = 0; p < Tv * Lv; ++p) {
        const int t = p >> 2, l = p & 3;
        const int par = t & 1, ppar = par ^ 1;
        const int cur = p & 1;

        // issue next phase's W staging into the other buffer (fully async)
        if (p + 1 < Tv * Lv) STAGE((p + 1) & 3, cur ^ 1);

        const float* xa = (l == 0)
            ? (t == 0 ? yT : hT + (size_t)(ppar * 4 + 3) * 32768)
            : hT + (size_t)(par * 4 + (l - 1)) * 32768;
        const float* ha = hT + (size_t)(ppar * 4 + l) * 32768;

        // 64 activation floats for batch b, k-slice (s&7)*64..: plain cached
        // float4 loads (coherence via the per-phase acquire fence below)
        const float4* actq = (const float4*)((s < 8) ? xa : ha);
        float4 av4[16];
#pragma unroll
        for (int j = 0; j < 16; ++j)
            av4[j] = actq[(size_t)((s & 7) * 16 + j) * 64 + b];

        // W from the staged LDS buffer, wave-uniform broadcast b128 reads
        const float* wl = wstg[cur] + s * 64;
        float acc[8];
#pragma unroll
        for (int col = 0; col < 8; ++col) {
            const float* wp = wl + col * 1024;
            float sum = 0.f;
#pragma unroll
            for (int j = 0; j < 16; ++j) {
                const float4 w4 = *(const float4*)(wp + j * 4);
                const float4 a  = av4[j];
                sum = fmaf(a.x, w4.x, sum);
                sum = fmaf(a.y, w4.y, sum);
                sum = fmaf(a.z, w4.z, sum);
                sum = fmaf(a.w, w4.w, sum);
            }
            acc[col] = sum;
        }

        // ---- one-pass gate reduce + epilogue (R13 verbatim) ----
        redA[s][b] = make_float4(acc[0], acc[1], acc[2], acc[3]);
        redB[s][b] = make_float4(acc[4], acc[5], acc[6], acc[7]);
        __syncthreads();   // red ready; also drains STAGE(p+1) (vmcnt)

        if (tid < 128) {
            const int hn = tid >> 6;
            const float4* plane = hn ? &redB[0][0] : &redA[0][0];
            int b2 = tid & 63;
            float gx = 0.f, gy = 0.f, gz = 0.f, gw = 0.f;
#pragma unroll
            for (int ss = 0; ss < 16; ++ss) {
                float4 r = plane[ss * 64 + b2];
                gx += r.x; gy += r.y; gz += r.z; gw += r.w;
            }
            float4 bb4 = *(const float4*)(biasC + l * G4 + bid * 8 + hn * 4);
            float ig = sigmoidf_(gx + bb4.x);
            float fg = sigmoidf_(gy + bb4.y);
            float gv = tanhf(gz + bb4.z);
            float og = sigmoidf_(gw + bb4.w);

            float cn = fg * cst[l][hn][b2] + ig * gv;
            cst[l][hn][b2] = cn;
            float hv = og * tanhf(cn);

            int n = bid * 2 + hn;
            __hip_atomic_store(
                &hT[(size_t)(par * 4 + l) * 32768 + ((n >> 2) * 64 + b2) * 4 + (n & 3)],
                hv, __ATOMIC_RELAXED, __HIP_MEMORY_SCOPE_AGENT);
            if (l == Lv - 1)
                out[((size_t)b2 * Tv + t) * Hv + n] = hv;
        }
        __syncthreads();   // epilogue stores drained (vmcnt) before arrival

        // ---- inter-block barrier (monotonic, spread counters) ----
        if (tid == 0)
            __hip_atomic_fetch_add(&bar8[(bid & 7) * 16], 1,
                                   __ATOMIC_RELEASE, __HIP_MEMORY_SCOPE_AGENT);
        if (tid < 8) {
            const int target = 32 * (p + 1);
            while (__hip_atomic_load(&bar8[tid * 16], __ATOMIC_RELAXED,
                                     __HIP_MEMORY_SCOPE_AGENT) < target)
                __builtin_amdgcn_s_sleep(2);
        }
        __syncthreads();
        // one invalidate per phase: drop stale L1/L2 act lines (W is in LDS,
        // so unlike R4 this invalidate costs ~nothing structurally)
        __builtin_amdgcn_fence(__ATOMIC_ACQUIRE, "agent");
    }
    #undef STAGE
}

extern "C" void kernel_launch(void* const* d_in, const int* in_sizes, int n_in,
                              void* d_out, int out_size, void* d_ws, size_t ws_size,
                              hipStream_t stream)
{
    const float* y   = (const float*)d_in[0];
    const float* h0  = (const float*)d_in[1];
    const float* c0  = (const float*)d_in[2];
    const float* Wih = (const float*)d_in[3];
    const float* Whh = (const float*)d_in[4];
    const float* bih = (const float*)d_in[5];
    const float* bhh = (const float*)d_in[6];
    float* out = (float*)d_out;

    char* ws = (char*)d_ws;
    float* wt    = (float*)(ws + WT_OFF);
    float* hT    = (float*)(ws + HT_OFF);
    float* yT    = (float*)(ws + YT_OFF);
    float* biasC = (float*)(ws + BIAS_OFF);
    int*   bar8  = (int*)(ws + BAR_OFF);

    hipMemsetAsync(ws + BAR_OFF, 0, 1024, stream);

    prep_wt<<<NBLK, 256, 0, stream>>>(Wih, Whh, wt);
    prep_bias<<<32, 256, 0, stream>>>(bih, bhh, biasC);
    prep_act<<<(32768 + 131072) / 256, 256, 0, stream>>>(y, h0, yT, hT);

    lstm_persist<<<NBLK, NTHR, 0, stream>>>(wt, biasC, yT, c0, hT, out, bar8);
}